// Round 1
// baseline (19028.618 us; speedup 1.0000x reference)
//
#include <hip/hip_runtime.h>
#include <math.h>

#define SEQ   512
#define BATCH 128
#define INP   512
#define HID   1024
#define G4    4096   // 4*HID
#define NOUT  4

// ---------------------------------------------------------------------------
// init: transpose h0,c0 [B][H] -> h_T,c_T [H][B]
// ---------------------------------------------------------------------------
__global__ void init_state(const float* __restrict__ h0, const float* __restrict__ c0,
                           float* __restrict__ hT, float* __restrict__ cT) {
  int idx = blockIdx.x * blockDim.x + threadIdx.x;  // < HID*BATCH
  int b = idx & (BATCH - 1);
  int j = idx >> 7;
  hT[j * BATCH + b] = h0[b * HID + j];
  cT[j * BATCH + b] = c0[b * HID + j];
}

// ---------------------------------------------------------------------------
// transpose a chunk of inputs: in [nrows][INP] -> xt [INP][nrows]
// (nrows = CT*BATCH; rows n = t*BATCH + b)
// ---------------------------------------------------------------------------
__global__ void transpose_in(const float* __restrict__ in, float* __restrict__ xt,
                             int nrows) {
  __shared__ float s[32][33];
  int tx = threadIdx.x & 31, ty = threadIdx.x >> 5;  // ty < 8
  int n0 = blockIdx.x * 32, i0 = blockIdx.y * 32;
#pragma unroll
  for (int r = 0; r < 4; r++) {
    int n = n0 + ty + 8 * r;
    s[ty + 8 * r][tx] = in[(size_t)n * INP + i0 + tx];
  }
  __syncthreads();
#pragma unroll
  for (int r = 0; r < 4; r++) {
    int i = i0 + ty + 8 * r;
    xt[(size_t)i * nrows + n0 + tx] = s[tx][ty + 8 * r];
  }
}

// ---------------------------------------------------------------------------
// gemm_xproj: C[4096][N] = W_ih[4096][512] @ Xt[512][N] + (b_ih + b_hh)
// tile 128x128, K-tile 32, thread = 8x8
// ---------------------------------------------------------------------------
__global__ __launch_bounds__(256, 3)
void gemm_xproj(const float* __restrict__ A, const float* __restrict__ Bm,
                const float* __restrict__ b_ih, const float* __restrict__ b_hh,
                float* __restrict__ C, int N) {
  __shared__ float As[32][128];
  __shared__ float Bs[32][128];
  int t = threadIdx.x;
  int g0 = blockIdx.x * 128;
  int n0 = blockIdx.y * 128;
  int mg = (t >> 4) * 8, nn = (t & 15) * 8;
  float acc[8][8] = {};
  for (int k0 = 0; k0 < INP; k0 += 32) {
#pragma unroll
    for (int r = 0; r < 4; r++) {
      int idx = t + 256 * r;            // 0..1023 : 128 rows x 8 float4
      int g = idx >> 3, i4 = idx & 7;
      float4 v = *(const float4*)&A[(size_t)(g0 + g) * INP + k0 + 4 * i4];
      As[4 * i4 + 0][g] = v.x; As[4 * i4 + 1][g] = v.y;
      As[4 * i4 + 2][g] = v.z; As[4 * i4 + 3][g] = v.w;
    }
#pragma unroll
    for (int r = 0; r < 4; r++) {
      int idx = t + 256 * r;            // 32 kk x 32 float4
      int kk = idx >> 5, n4 = idx & 31;
      *(float4*)&Bs[kk][4 * n4] = *(const float4*)&Bm[(size_t)(k0 + kk) * N + n0 + 4 * n4];
    }
    __syncthreads();
#pragma unroll 4
    for (int kk = 0; kk < 32; kk++) {
      float4 a0 = *(const float4*)&As[kk][mg];
      float4 a1 = *(const float4*)&As[kk][mg + 4];
      float4 bb0 = *(const float4*)&Bs[kk][nn];
      float4 bb1 = *(const float4*)&Bs[kk][nn + 4];
      float av[8] = {a0.x, a0.y, a0.z, a0.w, a1.x, a1.y, a1.z, a1.w};
      float bv[8] = {bb0.x, bb0.y, bb0.z, bb0.w, bb1.x, bb1.y, bb1.z, bb1.w};
#pragma unroll
      for (int i2 = 0; i2 < 8; i2++)
#pragma unroll
        for (int j2 = 0; j2 < 8; j2++)
          acc[i2][j2] = fmaf(av[i2], bv[j2], acc[i2][j2]);
    }
    __syncthreads();
  }
#pragma unroll
  for (int i2 = 0; i2 < 8; i2++) {
    int g = g0 + mg + i2;
    float bias = b_ih[g] + b_hh[g];
#pragma unroll
    for (int j2 = 0; j2 < 8; j2++) {
      C[(size_t)g * N + n0 + nn + j2] = acc[i2][j2] + bias;
    }
  }
}

// ---------------------------------------------------------------------------
// gemm_step: partial[kseg][mt*128+m][b] = W_hh(tile rows) @ h_T (K-slice)
// grid (32 m-tiles, 8 k-segments). Row order inside tile: m = jj*4 + gate,
// global W row = gate*HID + j0 + jj  (so cell_update finds all 4 gates
// of one j adjacent).
// ---------------------------------------------------------------------------
__global__ __launch_bounds__(256, 3)
void gemm_step(const float* __restrict__ W, const float* __restrict__ hT,
               float* __restrict__ part) {
  __shared__ float As[32][128];
  __shared__ float hs[32][128];
  int t = threadIdx.x;
  int mt = blockIdx.x;       // 0..31
  int kseg = blockIdx.y;     // 0..7
  int j0 = mt * 32;
  int mg = (t >> 4) * 8, nn = (t & 15) * 8;
  float acc[8][8] = {};
  for (int kt = 0; kt < 4; kt++) {
    int k0 = kseg * 128 + kt * 32;
#pragma unroll
    for (int r = 0; r < 4; r++) {
      int idx = t + 256 * r;
      int m = idx >> 3, i4 = idx & 7;
      int row = (m & 3) * HID + j0 + (m >> 2);
      float4 v = *(const float4*)&W[(size_t)row * HID + k0 + 4 * i4];
      As[4 * i4 + 0][m] = v.x; As[4 * i4 + 1][m] = v.y;
      As[4 * i4 + 2][m] = v.z; As[4 * i4 + 3][m] = v.w;
    }
#pragma unroll
    for (int r = 0; r < 4; r++) {
      int idx = t + 256 * r;
      int kk = idx >> 5, b4 = idx & 31;
      *(float4*)&hs[kk][4 * b4] = *(const float4*)&hT[(size_t)(k0 + kk) * BATCH + 4 * b4];
    }
    __syncthreads();
#pragma unroll 4
    for (int kk = 0; kk < 32; kk++) {
      float4 a0 = *(const float4*)&As[kk][mg];
      float4 a1 = *(const float4*)&As[kk][mg + 4];
      float4 h0v = *(const float4*)&hs[kk][nn];
      float4 h1v = *(const float4*)&hs[kk][nn + 4];
      float av[8] = {a0.x, a0.y, a0.z, a0.w, a1.x, a1.y, a1.z, a1.w};
      float hv[8] = {h0v.x, h0v.y, h0v.z, h0v.w, h1v.x, h1v.y, h1v.z, h1v.w};
#pragma unroll
      for (int i2 = 0; i2 < 8; i2++)
#pragma unroll
        for (int j2 = 0; j2 < 8; j2++)
          acc[i2][j2] = fmaf(av[i2], hv[j2], acc[i2][j2]);
    }
    __syncthreads();
  }
  float* dst = part + ((size_t)kseg * G4 + mt * 128) * BATCH;
#pragma unroll
  for (int i2 = 0; i2 < 8; i2++) {
    *(float4*)&dst[(size_t)(mg + i2) * BATCH + nn] =
        make_float4(acc[i2][0], acc[i2][1], acc[i2][2], acc[i2][3]);
    *(float4*)&dst[(size_t)(mg + i2) * BATCH + nn + 4] =
        make_float4(acc[i2][4], acc[i2][5], acc[i2][6], acc[i2][7]);
  }
}

// ---------------------------------------------------------------------------
// cell_update: reduce 8 K-partials + x_proj, apply LSTM cell, write h_T,c_T
// ---------------------------------------------------------------------------
__global__ void cell_update(const float* __restrict__ part, const float* __restrict__ xp,
                            int N, int tt, float* __restrict__ hT, float* __restrict__ cT) {
  int idx = blockIdx.x * blockDim.x + threadIdx.x;  // < HID*BATCH
  int b = idx & (BATCH - 1);
  int j = idx >> 7;
  int mt = j >> 5, jj = j & 31;
  int rowbase = mt * 128 + jj * 4;
  float pre[4];
#pragma unroll
  for (int g = 0; g < 4; g++) {
    float s = xp[(size_t)(g * HID + j) * N + (size_t)tt * BATCH + b];
#pragma unroll
    for (int p = 0; p < 8; p++)
      s += part[((size_t)p * G4 + rowbase + g) * BATCH + b];
    pre[g] = s;
  }
  float ig = 1.f / (1.f + expf(-pre[0]));
  float fg = 1.f / (1.f + expf(-pre[1]));
  float gg = tanhf(pre[2]);
  float og = 1.f / (1.f + expf(-pre[3]));
  float cn = fg * cT[idx] + ig * gg;
  cT[idx] = cn;
  hT[idx] = og * tanhf(cn);
}

// ---------------------------------------------------------------------------
// decode + softmax over batch dim (axis 0)
// ---------------------------------------------------------------------------
__global__ void decode_softmax(const float* __restrict__ hT, const float* __restrict__ Wd,
                               const float* __restrict__ bd, float* __restrict__ out) {
  __shared__ float lg[NOUT][BATCH];
  __shared__ float mx[NOUT], sm[NOUT];
  int t = threadIdx.x;  // 512 threads
  int b = t >> 2, o = t & 3;
  float s = bd[o];
  for (int j = 0; j < HID; j++) s += hT[j * BATCH + b] * Wd[o * HID + j];
  lg[o][b] = s;
  __syncthreads();
  if (t < NOUT) {
    float m = -1e30f;
    for (int b2 = 0; b2 < BATCH; b2++) m = fmaxf(m, lg[t][b2]);
    float ss = 0.f;
    for (int b2 = 0; b2 < BATCH; b2++) ss += expf(lg[t][b2] - m);
    mx[t] = m; sm[t] = ss;
  }
  __syncthreads();
  out[b * NOUT + o] = expf(lg[o][b] - mx[o]) / sm[o];
}

// ---------------------------------------------------------------------------
extern "C" void kernel_launch(void* const* d_in, const int* in_sizes, int n_in,
                              void* d_out, int out_size, void* d_ws, size_t ws_size,
                              hipStream_t stream) {
  const float* inputs = (const float*)d_in[0];
  const float* h0     = (const float*)d_in[1];
  const float* c0     = (const float*)d_in[2];
  const float* W_ih   = (const float*)d_in[3];
  const float* W_hh   = (const float*)d_in[4];
  const float* b_ih   = (const float*)d_in[5];
  const float* b_hh   = (const float*)d_in[6];
  const float* W_dec  = (const float*)d_in[7];
  const float* b_dec  = (const float*)d_in[8];
  float* out = (float*)d_out;

  char* w = (char*)d_ws;
  float* hT = (float*)w;   w += (size_t)HID * BATCH * 4;
  float* cT = (float*)w;   w += (size_t)HID * BATCH * 4;
  float* part = (float*)w; w += (size_t)8 * G4 * BATCH * 4;
  size_t used = (size_t)(w - (char*)d_ws);

  // chunk size over timesteps, sized to fit ws (deterministic: ws_size const)
  size_t per_ct = ((size_t)INP * BATCH + (size_t)G4 * BATCH) * 4;  // Xt + XP per step
  int CT = 1;
  if (ws_size > used) {
    size_t avail = (ws_size - used) / per_ct;
    for (int c = SEQ; c >= 1; c >>= 1)
      if ((size_t)c <= avail) { CT = c; break; }
  }
  float* Xt = (float*)w;   w += (size_t)INP * BATCH * CT * 4;
  float* XP = (float*)w;
  int N = CT * BATCH;

  init_state<<<HID * BATCH / 256, 256, 0, stream>>>(h0, c0, hT, cT);

  for (int t0 = 0; t0 < SEQ; t0 += CT) {
    transpose_in<<<dim3(N / 32, INP / 32), 256, 0, stream>>>(
        inputs + (size_t)t0 * BATCH * INP, Xt, N);
    gemm_xproj<<<dim3(G4 / 128, N / 128), 256, 0, stream>>>(
        W_ih, Xt, b_ih, b_hh, XP, N);
    for (int tt = 0; tt < CT; tt++) {
      gemm_step<<<dim3(32, 8), 256, 0, stream>>>(W_hh, hT, part);
      cell_update<<<HID * BATCH / 256, 256, 0, stream>>>(part, XP, N, tt, hT, cT);
    }
  }

  decode_softmax<<<1, 512, 0, stream>>>(hT, W_dec, b_dec, out);
}